// Round 7
// baseline (296.373 us; speedup 1.0000x reference)
//
#include <hip/hip_runtime.h>

// ============================================================================
// Causal MHA with RoPE. FP32 in/out; bf16 MFMA internally.
//   B=4 T=2048 D=1024 h=16 d_k=64, theta=10000
// R7 changes:
//  - flash: single-buffered K/V (2 barriers/iter, register prefetch), per-
//    (wave,half) P regions (removes intra-wave WAR serialization), truncating
//    P pack. LDS 44K->34K => 4 resident blocks/CU (whole grid resident).
//  - RoPE fused into gemm_qkv epilogue (pair exchange via shfl_xor(.,1)):
//    rope_qk kernels and Qlin/Klin round-trip removed.
// ============================================================================

typedef unsigned short u16;
typedef short short8 __attribute__((ext_vector_type(8)));
typedef float f32x4 __attribute__((ext_vector_type(4)));

#if defined(__has_builtin)
#if __has_builtin(__builtin_amdgcn_exp2f)
#define EXP2(x) __builtin_amdgcn_exp2f(x)
#else
#define EXP2(x) exp2f(x)
#endif
#else
#define EXP2(x) exp2f(x)
#endif

#define QSCALE 0.18033688011112042f  // (1/sqrt(64)) * log2(e)

__device__ __forceinline__ float bf2f(u16 u) {
  return __uint_as_float(((unsigned int)u) << 16);
}
__device__ __forceinline__ u16 f2bf(float f) {
  unsigned int x = __float_as_uint(f);
  x += 0x7fff + ((x >> 16) & 1);  // RNE
  return (u16)(x >> 16);
}

// async 16B global -> LDS (wave-uniform LDS base + lane*16) [m97/m104]
__device__ __forceinline__ void glds16(const u16* g, u16* l) {
  __builtin_amdgcn_global_load_lds(
      (const __attribute__((address_space(1))) unsigned int*)g,
      (__attribute__((address_space(3))) unsigned int*)l, 16, 0, 0);
}

// ---------------------------------------------------------------------------
// fp32 -> bf16 (RNE), 8 elements/thread.
// ---------------------------------------------------------------------------
__global__ __launch_bounds__(256) void cvt_bf16(const float* __restrict__ in,
                                                u16* __restrict__ out) {
  const int i = (blockIdx.x * 256 + threadIdx.x) * 8;
  const float4 a = *(const float4*)(in + i);
  const float4 b = *(const float4*)(in + i + 4);
  short8 o;
  o[0] = (short)f2bf(a.x); o[1] = (short)f2bf(a.y);
  o[2] = (short)f2bf(a.z); o[3] = (short)f2bf(a.w);
  o[4] = (short)f2bf(b.x); o[5] = (short)f2bf(b.y);
  o[6] = (short)f2bf(b.z); o[7] = (short)f2bf(b.w);
  *(short8*)(out + i) = o;
}

// ---------------------------------------------------------------------------
// Fused QKV NT GEMM + RoPE epilogue.
// W = packed [Wq;Wk;Wv] (3072x1024). Q/K tiles: RoPE rotate (fp32, pair via
// shfl_xor lane^1), Q also scaled by QSCALE, written to (b*16+h, t, 64).
// V tiles: plain bf16 to Vlin (b,t,1024). Grid (24,64).
// ---------------------------------------------------------------------------
__global__ __launch_bounds__(256) void gemm_qkv(const u16* __restrict__ A,
                                                const u16* __restrict__ W,
                                                const float2* __restrict__ tab,
                                                u16* __restrict__ Qr,
                                                u16* __restrict__ Kr,
                                                u16* __restrict__ Vd) {
  const int K = 1024;
  __shared__ __align__(16) u16 As[128 * 32];
  __shared__ __align__(16) u16 Bs[128 * 32];
  const int tid = threadIdx.x;
  const int m0 = blockIdx.y << 7;
  const int n0 = blockIdx.x << 7;
  const int w = tid >> 6, L = tid & 63;
  const int wm = (w >> 1) << 6, wn = (w & 1) << 6;
  const int lane15 = L & 15, quad = L >> 4;
  const int koff = quad << 3;

  f32x4 acc[4][4] = {};

  const int s0 = tid, s1 = tid + 256;
  const int r0 = s0 >> 2, c0 = (s0 & 3) << 3;
  const int r1 = s1 >> 2, c1 = (s1 & 3) << 3;
  const u16* A0 = A + (size_t)(m0 + r0) * K + c0;
  const u16* A1 = A + (size_t)(m0 + r1) * K + c1;
  const u16* B0 = W + (size_t)(n0 + r0) * K + c0;
  const u16* B1 = W + (size_t)(n0 + r1) * K + c1;
  u16* asd0 = &As[s0 * 8]; u16* asd1 = &As[s1 * 8];
  u16* bsd0 = &Bs[s0 * 8]; u16* bsd1 = &Bs[s1 * 8];

  for (int k0 = 0; k0 < K; k0 += 32) {
    __syncthreads();
    glds16(A0 + k0, asd0);
    glds16(A1 + k0, asd1);
    glds16(B0 + k0, bsd0);
    glds16(B1 + k0, bsd1);
    __syncthreads();
    short8 a[4], b[4];
#pragma unroll
    for (int mt = 0; mt < 4; ++mt)
      a[mt] = *(const short8*)&As[(wm + mt * 16 + lane15) * 32 + koff];
#pragma unroll
    for (int nt = 0; nt < 4; ++nt)
      b[nt] = *(const short8*)&Bs[(wn + nt * 16 + lane15) * 32 + koff];
#pragma unroll
    for (int mt = 0; mt < 4; ++mt)
#pragma unroll
      for (int nt = 0; nt < 4; ++nt)
        acc[mt][nt] =
            __builtin_amdgcn_mfma_f32_16x16x32_bf16(a[mt], b[nt], acc[mt][nt], 0, 0, 0);
  }

  const int sel = n0 >> 10;            // 0=Q, 1=K, 2=V (uniform per block)
  const int ncol0 = (n0 & 1023) + wn;
  if (sel == 2) {
#pragma unroll
    for (int mt = 0; mt < 4; ++mt) {
      const int rbase = m0 + wm + mt * 16 + (quad << 2);
#pragma unroll
      for (int nt = 0; nt < 4; ++nt) {
        const int col = ncol0 + nt * 16 + lane15;
#pragma unroll
        for (int r = 0; r < 4; ++r)
          Vd[(size_t)(rbase + r) * 1024 + col] = f2bf(acc[mt][nt][r]);
      }
    }
  } else {
    u16* dst = sel ? Kr : Qr;
    const float sc = sel ? 1.0f : QSCALE;
#pragma unroll
    for (int mt = 0; mt < 4; ++mt) {
      const int rbase = m0 + wm + mt * 16 + (quad << 2);
#pragma unroll
      for (int nt = 0; nt < 4; ++nt) {
        const int col = ncol0 + nt * 16 + lane15;
        const int h = col >> 6, dcol = col & 63, d2 = dcol >> 1;
#pragma unroll
        for (int r = 0; r < 4; ++r) {
          const int m = rbase + r;
          const int bb = m >> 11, tt = m & 2047;
          const float2 cs = tab[(tt << 5) + d2];
          const float self = acc[mt][nt][r];
          const float part = __shfl_xor(self, 1, 64);
          // even col: x1*cos - x2*sin ; odd col: x1*sin + x2*cos
          const float res = (dcol & 1) ? (part * cs.y + self * cs.x)
                                       : (self * cs.x - part * cs.y);
          dst[(((size_t)((bb * 16 + h) * 2048 + tt)) << 6) + dcol] = f2bf(res * sc);
        }
      }
    }
  }
}

// ---------------------------------------------------------------------------
// NT GEMM (out-proj): C[m][n] = sum_k A[m][k]*B[n][k], fp32 out.
// ---------------------------------------------------------------------------
__global__ __launch_bounds__(256) void gemm_bt(const u16* __restrict__ A,
                                               const u16* __restrict__ B,
                                               float* __restrict__ C,
                                               int M, int N, int K) {
  __shared__ __align__(16) u16 As[128 * 32];
  __shared__ __align__(16) u16 Bs[128 * 32];
  const int tid = threadIdx.x;
  const int m0 = blockIdx.y << 7;
  const int n0 = blockIdx.x << 7;
  const int w = tid >> 6, L = tid & 63;
  const int wm = (w >> 1) << 6, wn = (w & 1) << 6;
  const int lane15 = L & 15, quad = L >> 4;
  const int koff = quad << 3;

  f32x4 acc[4][4] = {};

  const int s0 = tid, s1 = tid + 256;
  const int r0 = s0 >> 2, c0 = (s0 & 3) << 3;
  const int r1 = s1 >> 2, c1 = (s1 & 3) << 3;
  const u16* A0 = A + (size_t)(m0 + r0) * K + c0;
  const u16* A1 = A + (size_t)(m0 + r1) * K + c1;
  const u16* B0 = B + (size_t)(n0 + r0) * K + c0;
  const u16* B1 = B + (size_t)(n0 + r1) * K + c1;
  u16* asd0 = &As[s0 * 8]; u16* asd1 = &As[s1 * 8];
  u16* bsd0 = &Bs[s0 * 8]; u16* bsd1 = &Bs[s1 * 8];

  for (int k0 = 0; k0 < K; k0 += 32) {
    __syncthreads();
    glds16(A0 + k0, asd0);
    glds16(A1 + k0, asd1);
    glds16(B0 + k0, bsd0);
    glds16(B1 + k0, bsd1);
    __syncthreads();
    short8 a[4], b[4];
#pragma unroll
    for (int mt = 0; mt < 4; ++mt)
      a[mt] = *(const short8*)&As[(wm + mt * 16 + lane15) * 32 + koff];
#pragma unroll
    for (int nt = 0; nt < 4; ++nt)
      b[nt] = *(const short8*)&Bs[(wn + nt * 16 + lane15) * 32 + koff];
#pragma unroll
    for (int mt = 0; mt < 4; ++mt)
#pragma unroll
      for (int nt = 0; nt < 4; ++nt)
        acc[mt][nt] =
            __builtin_amdgcn_mfma_f32_16x16x32_bf16(a[mt], b[nt], acc[mt][nt], 0, 0, 0);
  }

#pragma unroll
  for (int mt = 0; mt < 4; ++mt) {
    const int rbase = m0 + wm + mt * 16 + (quad << 2);
#pragma unroll
    for (int nt = 0; nt < 4; ++nt) {
      const int col = n0 + wn + nt * 16 + lane15;
#pragma unroll
      for (int r = 0; r < 4; ++r)
        C[(size_t)(rbase + r) * N + col] = acc[mt][nt][r];
    }
  }
}

// ---------------------------------------------------------------------------
// RoPE cos/sin table (double precision angles).
// ---------------------------------------------------------------------------
__global__ __launch_bounds__(256) void rope_table(const int* __restrict__ pos,
                                                  float2* __restrict__ tab) {
  const int gid = blockIdx.x * 256 + threadIdx.x;  // t*32 + d2
  const int d2 = gid & 31;
  const int t = gid >> 5;
  double inv = pow(10000.0, -(double)d2 / 32.0);
  double ang = (double)pos[t] * inv;
  tab[gid] = make_float2((float)cos(ang), (float)sin(ang));
}

// ---------------------------------------------------------------------------
// V transpose: (b,t,h*64+d) -> (b*16+h, d, t) via LDS 64x64 tile.
// ---------------------------------------------------------------------------
__global__ __launch_bounds__(256) void transpose_v(const u16* __restrict__ Vlin,
                                                   u16* __restrict__ Vt) {
  __shared__ __align__(16) u16 tile[64][68];
  const int tid = threadIdx.x;
  const int bh = blockIdx.y, b = bh >> 4, h = bh & 15;
  const int t0 = blockIdx.x << 6;
#pragma unroll
  for (int i = 0; i < 4; ++i) {
    int s = tid + (i << 8);
    int tl = s >> 4, c4 = (s & 15) << 2;
    *(uint2*)&tile[tl][c4] =
        *(const uint2*)(Vlin + (((size_t)(b * 2048 + t0 + tl)) << 10) + (h << 6) + c4);
  }
  __syncthreads();
#pragma unroll
  for (int i = 0; i < 4; ++i) {
    int s = tid + (i << 8);
    int d = s >> 4, t4 = (s & 15) << 2;
    uint2 o;
    o.x = (unsigned)tile[t4 + 0][d] | ((unsigned)tile[t4 + 1][d] << 16);
    o.y = (unsigned)tile[t4 + 2][d] | ((unsigned)tile[t4 + 3][d] << 16);
    *(uint2*)(Vt + (((size_t)(bh * 64 + d)) << 11) + t0 + t4) = o;
  }
}

// ---------------------------------------------------------------------------
// Flash attention v5 (causal). 1024 blocks: qt = 15-(id>>6), bh = id&63.
// Q-tile 128: wave w owns rows [qt*128+w*32,+32) as 2 halves of 16.
// Single-buffered K/V (register prefetch, 2 barriers/iter); per-(wave,half)
// P regions; K/V LDS rows padded to 72; truncating P pack; max-free softmax.
// LDS = 9216*2 + 16384 = 34816 B -> 4 blocks/CU resident.
// ---------------------------------------------------------------------------
__global__ __launch_bounds__(256) void flash_attn(const u16* __restrict__ Q,
                                                  const u16* __restrict__ Kk,
                                                  const u16* __restrict__ Vt,
                                                  u16* __restrict__ O) {
  __shared__ __align__(16) u16 Ksm[64 * 72];      // [key][d] pad 72
  __shared__ __align__(16) u16 Vsm[64 * 72];      // [d][key] pad 72
  __shared__ __align__(16) u16 Psm[8][16 * 64];   // per (wave,half) P
  const int tid = threadIdx.x;
  const int w = tid >> 6, L = tid & 63;
  const int lane15 = L & 15, quad = L >> 4;
  const int qt = 15 - (blockIdx.x >> 6);
  const int bh = blockIdx.x & 63;
  const int b = bh >> 4, h = bh & 15;
  const int rq = lane15 >> 2;  // row-quad for P read swizzle
  const int nkt = 2 * qt + 2;

  // staging chunks (16B): s covers [row=s>>3][col=(s&7)*8] of a 64x64 tile
  const int s0 = tid, s1 = tid + 256;
  const u16* kbase = Kk + ((size_t)bh << 17);
  const u16* kp0 = kbase + s0 * 8;
  const u16* kp1 = kbase + s1 * 8;
  const u16* vbase = Vt + ((size_t)bh << 17);
  const u16* vp0 = vbase + (size_t)(s0 >> 3) * 2048 + (s0 & 7) * 8;
  const u16* vp1 = vbase + (size_t)(s1 >> 3) * 2048 + (s1 & 7) * 8;
  const int d0 = (s0 >> 3) * 72 + (s0 & 7) * 8;   // padded LDS offsets
  const int d1 = (s1 >> 3) * 72 + (s1 & 7) * 8;

  // Q A-frags for the wave's 2 row-halves: A[m=lane15][k=quad*8+j]
  const size_t qrow = (size_t)bh * 2048 + qt * 128 + w * 32;
  short8 qa[2][2];
#pragma unroll
  for (int hf = 0; hf < 2; ++hf) {
    const size_t qb = (qrow + hf * 16 + lane15) << 6;
    qa[hf][0] = *(const short8*)(Q + qb + (quad << 3));
    qa[hf][1] = *(const short8*)(Q + qb + 32 + (quad << 3));
  }

  // preload tile 0
  uint4 kr0 = *(const uint4*)kp0;
  uint4 kr1 = *(const uint4*)kp1;
  uint4 vr0 = *(const uint4*)vp0;
  uint4 vr1 = *(const uint4*)vp1;
  *(uint4*)&Ksm[d0] = kr0; *(uint4*)&Ksm[d1] = kr1;
  *(uint4*)&Vsm[d0] = vr0; *(uint4*)&Vsm[d1] = vr1;
  __syncthreads();

  f32x4 o_acc[2][4] = {};
  float l_part[2][4] = {};

  for (int kt = 0; kt < nkt; ++kt) {
    if (kt + 1 < nkt) {  // register prefetch of next tile (covers whole iter)
      kr0 = *(const uint4*)(kp0 + (size_t)(kt + 1) * 4096);
      kr1 = *(const uint4*)(kp1 + (size_t)(kt + 1) * 4096);
      vr0 = *(const uint4*)(vp0 + (kt + 1) * 64);
      vr1 = *(const uint4*)(vp1 + (kt + 1) * 64);
    }

    // cache K B-frags (shared by both halves)
    short8 kb[4][2];
#pragma unroll
    for (int nt = 0; nt < 4; ++nt) {
      kb[nt][0] = *(const short8*)&Ksm[(nt * 16 + lane15) * 72 + (quad << 3)];
      kb[nt][1] = *(const short8*)&Ksm[(nt * 16 + lane15) * 72 + 32 + (quad << 3)];
    }

#pragma unroll
    for (int hf = 0; hf < 2; ++hf) {
      const int B0 = qt * 128 + w * 32 + hf * 16;   // first row of half
      if (kt * 64 > B0 + 15) continue;              // fully masked (uniform)
      u16* pw = Psm[w * 2 + hf];

      f32x4 sc[4];
#pragma unroll
      for (int nt = 0; nt < 4; ++nt) {
        f32x4 a = {};
        a = __builtin_amdgcn_mfma_f32_16x16x32_bf16(qa[hf][0], kb[nt][0], a, 0, 0, 0);
        a = __builtin_amdgcn_mfma_f32_16x16x32_bf16(qa[hf][1], kb[nt][1], a, 0, 0, 0);
        sc[nt] = a;
      }

      if (kt * 64 + 63 > B0) {  // diagonal: apply causal mask
#pragma unroll
        for (int nt = 0; nt < 4; ++nt)
#pragma unroll
          for (int r = 0; r < 4; ++r) {
            const int row = B0 + (quad << 2) + r;
            const int key = kt * 64 + nt * 16 + lane15;
            if (key > row) sc[nt][r] = -1e30f;
          }
      }

      // p = exp2(S'); accumulate l; truncate-pack bf16; swizzled store
      asm volatile("" ::: "memory");
#pragma unroll
      for (int nt = 0; nt < 4; ++nt) {
        const int colsw = ((nt ^ quad) << 4) + lane15;
#pragma unroll
        for (int r = 0; r < 4; ++r) {
          const float p = EXP2(sc[nt][r]);
          l_part[hf][r] += p;
          pw[((quad << 2) + r) * 64 + colsw] = (u16)(__float_as_uint(p) >> 16);
        }
      }
      asm volatile("" ::: "memory");

      // O_half += P V
#pragma unroll
      for (int ks = 0; ks < 2; ++ks) {
        const short8 pa =
            *(const short8*)&pw[lane15 * 64 + ((ks * 32 + quad * 8) ^ (rq << 4))];
#pragma unroll
        for (int dt = 0; dt < 4; ++dt) {
          const short8 vb =
              *(const short8*)&Vsm[(dt * 16 + lane15) * 72 + ks * 32 + quad * 8];
          o_acc[hf][dt] =
              __builtin_amdgcn_mfma_f32_16x16x32_bf16(pa, vb, o_acc[hf][dt], 0, 0, 0);
        }
      }
    }

    if (kt + 1 < nkt) {  // single-buffer exchange (uniform)
      __syncthreads();   // all waves done reading tile kt
      *(uint4*)&Ksm[d0] = kr0; *(uint4*)&Ksm[d1] = kr1;
      *(uint4*)&Vsm[d0] = vr0; *(uint4*)&Vsm[d1] = vr1;
      __syncthreads();   // tile kt+1 visible
    }
  }

  // epilogue per half: reduce l over 16 lanes, scale, store
#pragma unroll
  for (int hf = 0; hf < 2; ++hf) {
#pragma unroll
    for (int r = 0; r < 4; ++r) {
      float l = l_part[hf][r];
#pragma unroll
      for (int off = 1; off < 16; off <<= 1) l += __shfl_xor(l, off, 64);
      const float inv = 1.f / l;
      const int t = qt * 128 + w * 32 + hf * 16 + (quad << 2) + r;
      const size_t obase = (((size_t)b * 2048 + t) << 10) + (h << 6);
#pragma unroll
      for (int dt = 0; dt < 4; ++dt)
        O[obase + dt * 16 + lane15] = f2bf(o_acc[hf][dt][r] * inv);
    }
  }
}

// ---------------------------------------------------------------------------
extern "C" void kernel_launch(void* const* d_in, const int* in_sizes, int n_in,
                              void* d_out, int out_size, void* d_ws, size_t ws_size,
                              hipStream_t stream) {
  const float* X  = (const float*)d_in[0];
  const int* pos  = (const int*)d_in[1];
  const float* Wq = (const float*)d_in[2];
  const float* Wk = (const float*)d_in[3];
  const float* Wv = (const float*)d_in[4];
  const float* Wo = (const float*)d_in[5];
  float* out = (float*)d_out;

  char* ws = (char*)d_ws;
  const size_t SZ = (size_t)8192 * 1024 * sizeof(u16);  // 16 MB per (B,T,D) bf16
  const size_t WSZ = (size_t)1024 * 1024 * sizeof(u16); //  2 MB per (D,D) bf16
  u16* Vlin = (u16*)(ws + 0 * SZ);
  u16* Qr   = (u16*)(ws + 1 * SZ);
  u16* Kr   = (u16*)(ws + 2 * SZ);
  u16* Vt   = (u16*)(ws + 3 * SZ);
  u16* Xb   = (u16*)(ws + 4 * SZ);
  u16* Oh   = Vlin;  // Vlin dead after transpose_v
  char* wtail = ws + 5 * SZ;
  u16* Wqkvb = (u16*)(wtail);                 // packed [Wq;Wk;Wv] 3072x1024
  u16* Wob   = (u16*)(wtail + 3 * WSZ);
  float2* tab = (float2*)(wtail + 4 * WSZ);   // 512 KB

  const dim3 blk(256);

  cvt_bf16<<<4096, blk, 0, stream>>>(X, Xb);
  cvt_bf16<<<512, blk, 0, stream>>>(Wq, Wqkvb);
  cvt_bf16<<<512, blk, 0, stream>>>(Wk, Wqkvb + 1024 * 1024);
  cvt_bf16<<<512, blk, 0, stream>>>(Wv, Wqkvb + 2 * 1024 * 1024);
  cvt_bf16<<<512, blk, 0, stream>>>(Wo, Wob);
  rope_table<<<256, blk, 0, stream>>>(pos, tab);
  gemm_qkv<<<dim3(24, 64), blk, 0, stream>>>(Xb, Wqkvb, tab, Qr, Kr, Vlin);
  transpose_v<<<dim3(32, 64), blk, 0, stream>>>(Vlin, Vt);
  flash_attn<<<1024, blk, 0, stream>>>(Qr, Kr, Vt, Oh);
  gemm_bt<<<dim3(8, 64), blk, 0, stream>>>(Oh, Wob, out, 8192, 1024, 1024);
}

// Round 8
// 292.790 us; speedup vs baseline: 1.0122x; 1.0122x over previous
//
#include <hip/hip_runtime.h>

// ============================================================================
// Causal MHA with RoPE. FP32 in/out; bf16 MFMA internally.
//   B=4 T=2048 D=1024 h=16 d_k=64, theta=10000
// R8 changes:
//  - gemm_qkv RoPE epilogue: cos/sin computed INLINE (__sincosf from pos[] +
//    exp2f inv-freq) -- R7's tab[] gather was ~40us of L1 serialization
//    (64 scattered 8B loads/thread). rope_table kernel + tab deleted.
//  - out-proj gemm: 64x128 tile -> 1024 blocks = 4/CU (was 512 = 2/CU,
//    overlap-starved ~320 TF). B (2MB) fully L2-cached so extra re-reads free.
//  - flash unchanged (R7 diet verified: dropped out of top-5).
// ============================================================================

typedef unsigned short u16;
typedef short short8 __attribute__((ext_vector_type(8)));
typedef float f32x4 __attribute__((ext_vector_type(4)));

#if defined(__has_builtin)
#if __has_builtin(__builtin_amdgcn_exp2f)
#define EXP2(x) __builtin_amdgcn_exp2f(x)
#else
#define EXP2(x) exp2f(x)
#endif
#else
#define EXP2(x) exp2f(x)
#endif

#define QSCALE 0.18033688011112042f   // (1/sqrt(64)) * log2(e)
#define NEG_L2T_32 -0.4152410118609203f  // -log2(10000)/32

__device__ __forceinline__ float bf2f(u16 u) {
  return __uint_as_float(((unsigned int)u) << 16);
}
__device__ __forceinline__ u16 f2bf(float f) {
  unsigned int x = __float_as_uint(f);
  x += 0x7fff + ((x >> 16) & 1);  // RNE
  return (u16)(x >> 16);
}

// async 16B global -> LDS (wave-uniform LDS base + lane*16) [m97/m104]
__device__ __forceinline__ void glds16(const u16* g, u16* l) {
  __builtin_amdgcn_global_load_lds(
      (const __attribute__((address_space(1))) unsigned int*)g,
      (__attribute__((address_space(3))) unsigned int*)l, 16, 0, 0);
}

// ---------------------------------------------------------------------------
// fp32 -> bf16 (RNE), 8 elements/thread.
// ---------------------------------------------------------------------------
__global__ __launch_bounds__(256) void cvt_bf16(const float* __restrict__ in,
                                                u16* __restrict__ out) {
  const int i = (blockIdx.x * 256 + threadIdx.x) * 8;
  const float4 a = *(const float4*)(in + i);
  const float4 b = *(const float4*)(in + i + 4);
  short8 o;
  o[0] = (short)f2bf(a.x); o[1] = (short)f2bf(a.y);
  o[2] = (short)f2bf(a.z); o[3] = (short)f2bf(a.w);
  o[4] = (short)f2bf(b.x); o[5] = (short)f2bf(b.y);
  o[6] = (short)f2bf(b.z); o[7] = (short)f2bf(b.w);
  *(short8*)(out + i) = o;
}

// ---------------------------------------------------------------------------
// Fused QKV NT GEMM + inline-RoPE epilogue.
// W = packed [Wq;Wk;Wv] (3072x1024). Q/K tiles: RoPE rotate in fp32 (pair via
// shfl_xor lane^1, cos/sin via __sincosf of pos[t]*invfreq), Q scaled by
// QSCALE, written to (b*16+h, t, 64). V: plain bf16 to Vlin. Grid (24,64).
// ---------------------------------------------------------------------------
__global__ __launch_bounds__(256) void gemm_qkv(const u16* __restrict__ A,
                                                const u16* __restrict__ W,
                                                const int* __restrict__ pos,
                                                u16* __restrict__ Qr,
                                                u16* __restrict__ Kr,
                                                u16* __restrict__ Vd) {
  const int K = 1024;
  __shared__ __align__(16) u16 As[128 * 32];
  __shared__ __align__(16) u16 Bs[128 * 32];
  const int tid = threadIdx.x;
  const int m0 = blockIdx.y << 7;
  const int n0 = blockIdx.x << 7;
  const int w = tid >> 6, L = tid & 63;
  const int wm = (w >> 1) << 6, wn = (w & 1) << 6;
  const int lane15 = L & 15, quad = L >> 4;
  const int koff = quad << 3;

  f32x4 acc[4][4] = {};

  const int s0 = tid, s1 = tid + 256;
  const int r0 = s0 >> 2, c0 = (s0 & 3) << 3;
  const int r1 = s1 >> 2, c1 = (s1 & 3) << 3;
  const u16* A0 = A + (size_t)(m0 + r0) * K + c0;
  const u16* A1 = A + (size_t)(m0 + r1) * K + c1;
  const u16* B0 = W + (size_t)(n0 + r0) * K + c0;
  const u16* B1 = W + (size_t)(n0 + r1) * K + c1;
  u16* asd0 = &As[s0 * 8]; u16* asd1 = &As[s1 * 8];
  u16* bsd0 = &Bs[s0 * 8]; u16* bsd1 = &Bs[s1 * 8];

  for (int k0 = 0; k0 < K; k0 += 32) {
    __syncthreads();
    glds16(A0 + k0, asd0);
    glds16(A1 + k0, asd1);
    glds16(B0 + k0, bsd0);
    glds16(B1 + k0, bsd1);
    __syncthreads();
    short8 a[4], b[4];
#pragma unroll
    for (int mt = 0; mt < 4; ++mt)
      a[mt] = *(const short8*)&As[(wm + mt * 16 + lane15) * 32 + koff];
#pragma unroll
    for (int nt = 0; nt < 4; ++nt)
      b[nt] = *(const short8*)&Bs[(wn + nt * 16 + lane15) * 32 + koff];
#pragma unroll
    for (int mt = 0; mt < 4; ++mt)
#pragma unroll
      for (int nt = 0; nt < 4; ++nt)
        acc[mt][nt] =
            __builtin_amdgcn_mfma_f32_16x16x32_bf16(a[mt], b[nt], acc[mt][nt], 0, 0, 0);
  }

  const int sel = n0 >> 10;            // 0=Q, 1=K, 2=V (uniform per block)
  const int ncol0 = (n0 & 1023) + wn;
  if (sel == 2) {
#pragma unroll
    for (int mt = 0; mt < 4; ++mt) {
      const int rbase = m0 + wm + mt * 16 + (quad << 2);
#pragma unroll
      for (int nt = 0; nt < 4; ++nt) {
        const int col = ncol0 + nt * 16 + lane15;
#pragma unroll
        for (int r = 0; r < 4; ++r)
          Vd[(size_t)(rbase + r) * 1024 + col] = f2bf(acc[mt][nt][r]);
      }
    }
  } else {
    u16* dst = sel ? Kr : Qr;
    const float sc = sel ? 1.0f : QSCALE;
    float invf[4];
#pragma unroll
    for (int nt = 0; nt < 4; ++nt) {
      const int d2 = ((ncol0 + nt * 16 + lane15) & 63) >> 1;
      invf[nt] = EXP2((float)d2 * NEG_L2T_32);
    }
#pragma unroll
    for (int mt = 0; mt < 4; ++mt) {
      const int rbase = m0 + wm + mt * 16 + (quad << 2);
#pragma unroll
      for (int r = 0; r < 4; ++r) {
        const int m = rbase + r;
        const int bb = m >> 11, tt = m & 2047;
        const float posf = (float)pos[tt];
#pragma unroll
        for (int nt = 0; nt < 4; ++nt) {
          const int col = ncol0 + nt * 16 + lane15;
          const int h = col >> 6, dcol = col & 63;
          float sn, cn;
          __sincosf(posf * invf[nt], &sn, &cn);
          const float self = acc[mt][nt][r];
          const float part = __shfl_xor(self, 1, 64);  // partner of RoPE pair
          const float res = (dcol & 1) ? (part * sn + self * cn)
                                       : (self * cn - part * sn);
          dst[(((size_t)((bb * 16 + h) * 2048 + tt)) << 6) + dcol] = f2bf(res * sc);
        }
      }
    }
  }
}

// ---------------------------------------------------------------------------
// NT GEMM (out-proj): 64x128 tile -> 1024 blocks (4/CU). fp32 out.
// ---------------------------------------------------------------------------
__global__ __launch_bounds__(256) void gemm_bt(const u16* __restrict__ A,
                                               const u16* __restrict__ B,
                                               float* __restrict__ C,
                                               int M, int N, int K) {
  __shared__ __align__(16) u16 As[64 * 32];    // 4 KB
  __shared__ __align__(16) u16 Bs[128 * 32];   // 8 KB
  const int tid = threadIdx.x;
  const int m0 = blockIdx.y << 6;
  const int n0 = blockIdx.x << 7;
  const int w = tid >> 6, L = tid & 63;
  const int wm = (w >> 1) << 5, wn = (w & 1) << 6;  // wave: 32x64
  const int lane15 = L & 15, quad = L >> 4;
  const int koff = quad << 3;

  f32x4 acc[2][4] = {};

  const int s0 = tid, s1 = tid + 256;
  const u16* A0 = A + (size_t)(m0 + (s0 >> 2)) * K + ((s0 & 3) << 3);
  const u16* B0 = B + (size_t)(n0 + (s0 >> 2)) * K + ((s0 & 3) << 3);
  const u16* B1 = B + (size_t)(n0 + (s1 >> 2)) * K + ((s1 & 3) << 3);
  u16* asd0 = &As[s0 * 8];
  u16* bsd0 = &Bs[s0 * 8]; u16* bsd1 = &Bs[s1 * 8];

  for (int k0 = 0; k0 < K; k0 += 32) {
    __syncthreads();
    glds16(A0 + k0, asd0);
    glds16(B0 + k0, bsd0);
    glds16(B1 + k0, bsd1);
    __syncthreads();
    short8 a[2], b[4];
#pragma unroll
    for (int mt = 0; mt < 2; ++mt)
      a[mt] = *(const short8*)&As[(wm + mt * 16 + lane15) * 32 + koff];
#pragma unroll
    for (int nt = 0; nt < 4; ++nt)
      b[nt] = *(const short8*)&Bs[(wn + nt * 16 + lane15) * 32 + koff];
#pragma unroll
    for (int mt = 0; mt < 2; ++mt)
#pragma unroll
      for (int nt = 0; nt < 4; ++nt)
        acc[mt][nt] =
            __builtin_amdgcn_mfma_f32_16x16x32_bf16(a[mt], b[nt], acc[mt][nt], 0, 0, 0);
  }

#pragma unroll
  for (int mt = 0; mt < 2; ++mt) {
    const int rbase = m0 + wm + mt * 16 + (quad << 2);
#pragma unroll
    for (int nt = 0; nt < 4; ++nt) {
      const int col = n0 + wn + nt * 16 + lane15;
#pragma unroll
      for (int r = 0; r < 4; ++r)
        C[(size_t)(rbase + r) * N + col] = acc[mt][nt][r];
    }
  }
}

// ---------------------------------------------------------------------------
// V transpose: (b,t,h*64+d) -> (b*16+h, d, t) via LDS 64x64 tile.
// ---------------------------------------------------------------------------
__global__ __launch_bounds__(256) void transpose_v(const u16* __restrict__ Vlin,
                                                   u16* __restrict__ Vt) {
  __shared__ __align__(16) u16 tile[64][68];
  const int tid = threadIdx.x;
  const int bh = blockIdx.y, b = bh >> 4, h = bh & 15;
  const int t0 = blockIdx.x << 6;
#pragma unroll
  for (int i = 0; i < 4; ++i) {
    int s = tid + (i << 8);
    int tl = s >> 4, c4 = (s & 15) << 2;
    *(uint2*)&tile[tl][c4] =
        *(const uint2*)(Vlin + (((size_t)(b * 2048 + t0 + tl)) << 10) + (h << 6) + c4);
  }
  __syncthreads();
#pragma unroll
  for (int i = 0; i < 4; ++i) {
    int s = tid + (i << 8);
    int d = s >> 4, t4 = (s & 15) << 2;
    uint2 o;
    o.x = (unsigned)tile[t4 + 0][d] | ((unsigned)tile[t4 + 1][d] << 16);
    o.y = (unsigned)tile[t4 + 2][d] | ((unsigned)tile[t4 + 3][d] << 16);
    *(uint2*)(Vt + (((size_t)(bh * 64 + d)) << 11) + t0 + t4) = o;
  }
}

// ---------------------------------------------------------------------------
// Flash attention v5 (causal). 1024 blocks: qt = 15-(id>>6), bh = id&63.
// Q-tile 128: wave w owns rows [qt*128+w*32,+32) as 2 halves of 16.
// Single-buffered K/V (register prefetch, 2 barriers/iter); per-(wave,half)
// P regions; K/V LDS rows padded to 72; truncating P pack; max-free softmax.
// LDS = 34816 B -> 4 blocks/CU resident.
// ---------------------------------------------------------------------------
__global__ __launch_bounds__(256) void flash_attn(const u16* __restrict__ Q,
                                                  const u16* __restrict__ Kk,
                                                  const u16* __restrict__ Vt,
                                                  u16* __restrict__ O) {
  __shared__ __align__(16) u16 Ksm[64 * 72];      // [key][d] pad 72
  __shared__ __align__(16) u16 Vsm[64 * 72];      // [d][key] pad 72
  __shared__ __align__(16) u16 Psm[8][16 * 64];   // per (wave,half) P
  const int tid = threadIdx.x;
  const int w = tid >> 6, L = tid & 63;
  const int lane15 = L & 15, quad = L >> 4;
  const int qt = 15 - (blockIdx.x >> 6);
  const int bh = blockIdx.x & 63;
  const int b = bh >> 4, h = bh & 15;
  const int rq = lane15 >> 2;  // row-quad for P read swizzle
  const int nkt = 2 * qt + 2;

  const int s0 = tid, s1 = tid + 256;
  const u16* kbase = Kk + ((size_t)bh << 17);
  const u16* kp0 = kbase + s0 * 8;
  const u16* kp1 = kbase + s1 * 8;
  const u16* vbase = Vt + ((size_t)bh << 17);
  const u16* vp0 = vbase + (size_t)(s0 >> 3) * 2048 + (s0 & 7) * 8;
  const u16* vp1 = vbase + (size_t)(s1 >> 3) * 2048 + (s1 & 7) * 8;
  const int d0 = (s0 >> 3) * 72 + (s0 & 7) * 8;
  const int d1 = (s1 >> 3) * 72 + (s1 & 7) * 8;

  const size_t qrow = (size_t)bh * 2048 + qt * 128 + w * 32;
  short8 qa[2][2];
#pragma unroll
  for (int hf = 0; hf < 2; ++hf) {
    const size_t qb = (qrow + hf * 16 + lane15) << 6;
    qa[hf][0] = *(const short8*)(Q + qb + (quad << 3));
    qa[hf][1] = *(const short8*)(Q + qb + 32 + (quad << 3));
  }

  uint4 kr0 = *(const uint4*)kp0;
  uint4 kr1 = *(const uint4*)kp1;
  uint4 vr0 = *(const uint4*)vp0;
  uint4 vr1 = *(const uint4*)vp1;
  *(uint4*)&Ksm[d0] = kr0; *(uint4*)&Ksm[d1] = kr1;
  *(uint4*)&Vsm[d0] = vr0; *(uint4*)&Vsm[d1] = vr1;
  __syncthreads();

  f32x4 o_acc[2][4] = {};
  float l_part[2][4] = {};

  for (int kt = 0; kt < nkt; ++kt) {
    if (kt + 1 < nkt) {
      kr0 = *(const uint4*)(kp0 + (size_t)(kt + 1) * 4096);
      kr1 = *(const uint4*)(kp1 + (size_t)(kt + 1) * 4096);
      vr0 = *(const uint4*)(vp0 + (kt + 1) * 64);
      vr1 = *(const uint4*)(vp1 + (kt + 1) * 64);
    }

    short8 kb[4][2];
#pragma unroll
    for (int nt = 0; nt < 4; ++nt) {
      kb[nt][0] = *(const short8*)&Ksm[(nt * 16 + lane15) * 72 + (quad << 3)];
      kb[nt][1] = *(const short8*)&Ksm[(nt * 16 + lane15) * 72 + 32 + (quad << 3)];
    }

#pragma unroll
    for (int hf = 0; hf < 2; ++hf) {
      const int B0 = qt * 128 + w * 32 + hf * 16;
      if (kt * 64 > B0 + 15) continue;
      u16* pw = Psm[w * 2 + hf];

      f32x4 sc[4];
#pragma unroll
      for (int nt = 0; nt < 4; ++nt) {
        f32x4 a = {};
        a = __builtin_amdgcn_mfma_f32_16x16x32_bf16(qa[hf][0], kb[nt][0], a, 0, 0, 0);
        a = __builtin_amdgcn_mfma_f32_16x16x32_bf16(qa[hf][1], kb[nt][1], a, 0, 0, 0);
        sc[nt] = a;
      }

      if (kt * 64 + 63 > B0) {
#pragma unroll
        for (int nt = 0; nt < 4; ++nt)
#pragma unroll
          for (int r = 0; r < 4; ++r) {
            const int row = B0 + (quad << 2) + r;
            const int key = kt * 64 + nt * 16 + lane15;
            if (key > row) sc[nt][r] = -1e30f;
          }
      }

      asm volatile("" ::: "memory");
#pragma unroll
      for (int nt = 0; nt < 4; ++nt) {
        const int colsw = ((nt ^ quad) << 4) + lane15;
#pragma unroll
        for (int r = 0; r < 4; ++r) {
          const float p = EXP2(sc[nt][r]);
          l_part[hf][r] += p;
          pw[((quad << 2) + r) * 64 + colsw] = (u16)(__float_as_uint(p) >> 16);
        }
      }
      asm volatile("" ::: "memory");

#pragma unroll
      for (int ks = 0; ks < 2; ++ks) {
        const short8 pa =
            *(const short8*)&pw[lane15 * 64 + ((ks * 32 + quad * 8) ^ (rq << 4))];
#pragma unroll
        for (int dt = 0; dt < 4; ++dt) {
          const short8 vb =
              *(const short8*)&Vsm[(dt * 16 + lane15) * 72 + ks * 32 + quad * 8];
          o_acc[hf][dt] =
              __builtin_amdgcn_mfma_f32_16x16x32_bf16(pa, vb, o_acc[hf][dt], 0, 0, 0);
        }
      }
    }

    if (kt + 1 < nkt) {
      __syncthreads();
      *(uint4*)&Ksm[d0] = kr0; *(uint4*)&Ksm[d1] = kr1;
      *(uint4*)&Vsm[d0] = vr0; *(uint4*)&Vsm[d1] = vr1;
      __syncthreads();
    }
  }

#pragma unroll
  for (int hf = 0; hf < 2; ++hf) {
#pragma unroll
    for (int r = 0; r < 4; ++r) {
      float l = l_part[hf][r];
#pragma unroll
      for (int off = 1; off < 16; off <<= 1) l += __shfl_xor(l, off, 64);
      const float inv = 1.f / l;
      const int t = qt * 128 + w * 32 + hf * 16 + (quad << 2) + r;
      const size_t obase = (((size_t)b * 2048 + t) << 10) + (h << 6);
#pragma unroll
      for (int dt = 0; dt < 4; ++dt)
        O[obase + dt * 16 + lane15] = f2bf(o_acc[hf][dt][r] * inv);
    }
  }
}

// ---------------------------------------------------------------------------
extern "C" void kernel_launch(void* const* d_in, const int* in_sizes, int n_in,
                              void* d_out, int out_size, void* d_ws, size_t ws_size,
                              hipStream_t stream) {
  const float* X  = (const float*)d_in[0];
  const int* pos  = (const int*)d_in[1];
  const float* Wq = (const float*)d_in[2];
  const float* Wk = (const float*)d_in[3];
  const float* Wv = (const float*)d_in[4];
  const float* Wo = (const float*)d_in[5];
  float* out = (float*)d_out;

  char* ws = (char*)d_ws;
  const size_t SZ = (size_t)8192 * 1024 * sizeof(u16);  // 16 MB per (B,T,D) bf16
  const size_t WSZ = (size_t)1024 * 1024 * sizeof(u16); //  2 MB per (D,D) bf16
  u16* Vlin = (u16*)(ws + 0 * SZ);
  u16* Qr   = (u16*)(ws + 1 * SZ);
  u16* Kr   = (u16*)(ws + 2 * SZ);
  u16* Vt   = (u16*)(ws + 3 * SZ);
  u16* Xb   = (u16*)(ws + 4 * SZ);
  u16* Oh   = Vlin;  // Vlin dead after transpose_v
  char* wtail = ws + 5 * SZ;
  u16* Wqkvb = (u16*)(wtail);                 // packed [Wq;Wk;Wv] 3072x1024
  u16* Wob   = (u16*)(wtail + 3 * WSZ);

  const dim3 blk(256);

  cvt_bf16<<<4096, blk, 0, stream>>>(X, Xb);
  cvt_bf16<<<512, blk, 0, stream>>>(Wq, Wqkvb);
  cvt_bf16<<<512, blk, 0, stream>>>(Wk, Wqkvb + 1024 * 1024);
  cvt_bf16<<<512, blk, 0, stream>>>(Wv, Wqkvb + 2 * 1024 * 1024);
  cvt_bf16<<<512, blk, 0, stream>>>(Wo, Wob);
  gemm_qkv<<<dim3(24, 64), blk, 0, stream>>>(Xb, Wqkvb, pos, Qr, Kr, Vlin);
  transpose_v<<<dim3(32, 64), blk, 0, stream>>>(Vlin, Vt);
  flash_attn<<<1024, blk, 0, stream>>>(Qr, Kr, Vt, Oh);
  gemm_bt<<<dim3(8, 128), blk, 0, stream>>>(Oh, Wob, out, 8192, 1024, 1024);
}

// Round 9
// 271.101 us; speedup vs baseline: 1.0932x; 1.0800x over previous
//
#include <hip/hip_runtime.h>

// ============================================================================
// Causal MHA with RoPE. FP32 in/out; bf16 MFMA internally.
//   B=4 T=2048 D=1024 h=16 d_k=64, theta=10000
// R9 changes:
//  - gemm_qkv: BK=64 (32 MFMA per barrier pair, 16 K-iters; was 16/32) with
//    XOR chunk swizzle (c ^ (row&7)) so ds_read_b128 stays conflict-free
//    while global_load_lds keeps its mandatory linear LDS layout (the lane
//    *source* addresses are permuted within each 128B row segment -> same
//    coalescing). LDS 32 KB single-buffered (m132: 64KB dbuf kills occupancy).
//  - 5 cvt launches fused into one cvt_all (region-uniform blocks).
//  - flash / transpose_v / gemm_bt unchanged (isolation).
// ============================================================================

typedef unsigned short u16;
typedef short short8 __attribute__((ext_vector_type(8)));
typedef float f32x4 __attribute__((ext_vector_type(4)));

#if defined(__has_builtin)
#if __has_builtin(__builtin_amdgcn_exp2f)
#define EXP2(x) __builtin_amdgcn_exp2f(x)
#else
#define EXP2(x) exp2f(x)
#endif
#else
#define EXP2(x) exp2f(x)
#endif

#define QSCALE 0.18033688011112042f     // (1/sqrt(64)) * log2(e)
#define NEG_L2T_32 -0.4152410118609203f // -log2(10000)/32

__device__ __forceinline__ float bf2f(u16 u) {
  return __uint_as_float(((unsigned int)u) << 16);
}
__device__ __forceinline__ u16 f2bf(float f) {
  unsigned int x = __float_as_uint(f);
  x += 0x7fff + ((x >> 16) & 1);  // RNE
  return (u16)(x >> 16);
}

// async 16B global -> LDS (wave-uniform LDS base + lane*16) [m97/m104]
__device__ __forceinline__ void glds16(const u16* g, u16* l) {
  __builtin_amdgcn_global_load_lds(
      (const __attribute__((address_space(1))) unsigned int*)g,
      (__attribute__((address_space(3))) unsigned int*)l, 16, 0, 0);
}

// ---------------------------------------------------------------------------
// Fused fp32->bf16 for all inputs in one launch. Regions (elems):
// [0,8M) X->Xb ; [8M,9M) Wq ; [9M,10M) Wk ; [10M,11M) Wv -> Wqkvb packed;
// [11M,12M) Wo->Wob. Block = 2048 elems, region-uniform (1M boundaries).
// ---------------------------------------------------------------------------
__global__ __launch_bounds__(256) void cvt_all(
    const float* __restrict__ X, const float* __restrict__ Wq,
    const float* __restrict__ Wk, const float* __restrict__ Wv,
    const float* __restrict__ Wo, u16* __restrict__ Xb,
    u16* __restrict__ Wqkvb, u16* __restrict__ Wob) {
  const int gid = blockIdx.x * 256 + threadIdx.x;
  const int i = gid * 8;
  const int M1 = 1 << 20;
  const float* src;
  u16* dst;
  int off;
  if (i < 8 * M1)        { src = X;  dst = Xb;            off = 0; }
  else if (i < 9 * M1)   { src = Wq; dst = Wqkvb;         off = 8 * M1; }
  else if (i < 10 * M1)  { src = Wk; dst = Wqkvb + M1;    off = 9 * M1; }
  else if (i < 11 * M1)  { src = Wv; dst = Wqkvb + 2*M1;  off = 10 * M1; }
  else                   { src = Wo; dst = Wob;           off = 11 * M1; }
  const int j = i - off;
  const float4 a = *(const float4*)(src + j);
  const float4 b = *(const float4*)(src + j + 4);
  short8 o;
  o[0] = (short)f2bf(a.x); o[1] = (short)f2bf(a.y);
  o[2] = (short)f2bf(a.z); o[3] = (short)f2bf(a.w);
  o[4] = (short)f2bf(b.x); o[5] = (short)f2bf(b.y);
  o[6] = (short)f2bf(b.z); o[7] = (short)f2bf(b.w);
  *(short8*)(dst + j) = o;
}

// ---------------------------------------------------------------------------
// Fused QKV NT GEMM + inline-RoPE epilogue.  BK=64, XOR-swizzled LDS.
// W = packed [Wq;Wk;Wv] (3072x1024). Grid (24,64).
// LDS tile [128 rows][8 chunks of 16B]; chunk c of row r holds global chunk
// c ^ (r&7). glds16 dest stays linear (chunk s at byte 16*s); the *global*
// source per lane is permuted within the same 128B segment (coalescing kept).
// ds_read addresses apply the same XOR -> 2 lanes per 4-bank group (free).
// ---------------------------------------------------------------------------
__global__ __launch_bounds__(256) void gemm_qkv(const u16* __restrict__ A,
                                                const u16* __restrict__ W,
                                                const int* __restrict__ pos,
                                                u16* __restrict__ Qr,
                                                u16* __restrict__ Kr,
                                                u16* __restrict__ Vd) {
  const int K = 1024;
  __shared__ __align__(16) u16 As[128 * 64];   // 16 KB
  __shared__ __align__(16) u16 Bs[128 * 64];   // 16 KB
  const int tid = threadIdx.x;
  const int m0 = blockIdx.y << 7;
  const int n0 = blockIdx.x << 7;
  const int w = tid >> 6, L = tid & 63;
  const int wm = (w >> 1) << 6, wn = (w & 1) << 6;
  const int lane15 = L & 15, quad = L >> 4;

  f32x4 acc[4][4] = {};

  // staging: 4 chunks of A and 4 of B per thread (1024 chunks per tile)
  const u16* Ap[4]; const u16* Bp[4];
  u16* Al[4]; u16* Bl[4];
#pragma unroll
  for (int i = 0; i < 4; ++i) {
    const int s = tid + (i << 8);
    const int row = s >> 3;
    const int c = ((s & 7) ^ (row & 7)) << 3;   // swizzled source chunk
    Ap[i] = A + (size_t)(m0 + row) * K + c;
    Bp[i] = W + (size_t)(n0 + row) * K + c;
    Al[i] = &As[s * 8];
    Bl[i] = &Bs[s * 8];
  }

  // ds_read offsets (constant per thread): rows wm/wn + mt*16 + lane15,
  // k-chunk (ks? quad+4 : quad) ^ (row&7)
  int offA[4][2], offB[4][2];
#pragma unroll
  for (int mt = 0; mt < 4; ++mt) {
    const int ra = wm + mt * 16 + lane15;
    const int rb = wn + mt * 16 + lane15;
    offA[mt][0] = ra * 64 + ((quad ^ (ra & 7)) << 3);
    offA[mt][1] = ra * 64 + (((quad + 4) ^ (ra & 7)) << 3);
    offB[mt][0] = rb * 64 + ((quad ^ (rb & 7)) << 3);
    offB[mt][1] = rb * 64 + (((quad + 4) ^ (rb & 7)) << 3);
  }

  for (int k0 = 0; k0 < K; k0 += 64) {
    __syncthreads();
#pragma unroll
    for (int i = 0; i < 4; ++i) glds16(Ap[i] + k0, Al[i]);
#pragma unroll
    for (int i = 0; i < 4; ++i) glds16(Bp[i] + k0, Bl[i]);
    __syncthreads();
#pragma unroll
    for (int ks = 0; ks < 2; ++ks) {
      short8 a[4], b[4];
#pragma unroll
      for (int mt = 0; mt < 4; ++mt) a[mt] = *(const short8*)&As[offA[mt][ks]];
#pragma unroll
      for (int nt = 0; nt < 4; ++nt) b[nt] = *(const short8*)&Bs[offB[nt][ks]];
#pragma unroll
      for (int mt = 0; mt < 4; ++mt)
#pragma unroll
        for (int nt = 0; nt < 4; ++nt)
          acc[mt][nt] =
              __builtin_amdgcn_mfma_f32_16x16x32_bf16(a[mt], b[nt], acc[mt][nt], 0, 0, 0);
    }
  }

  const int sel = n0 >> 10;            // 0=Q, 1=K, 2=V (uniform per block)
  const int ncol0 = (n0 & 1023) + wn;
  if (sel == 2) {
#pragma unroll
    for (int mt = 0; mt < 4; ++mt) {
      const int rbase = m0 + wm + mt * 16 + (quad << 2);
#pragma unroll
      for (int nt = 0; nt < 4; ++nt) {
        const int col = ncol0 + nt * 16 + lane15;
#pragma unroll
        for (int r = 0; r < 4; ++r)
          Vd[(size_t)(rbase + r) * 1024 + col] = f2bf(acc[mt][nt][r]);
      }
    }
  } else {
    u16* dst = sel ? Kr : Qr;
    const float sc = sel ? 1.0f : QSCALE;
    float invf[4];
#pragma unroll
    for (int nt = 0; nt < 4; ++nt) {
      const int d2 = ((ncol0 + nt * 16 + lane15) & 63) >> 1;
      invf[nt] = EXP2((float)d2 * NEG_L2T_32);
    }
#pragma unroll
    for (int mt = 0; mt < 4; ++mt) {
      const int rbase = m0 + wm + mt * 16 + (quad << 2);
#pragma unroll
      for (int r = 0; r < 4; ++r) {
        const int m = rbase + r;
        const int bb = m >> 11, tt = m & 2047;
        const float posf = (float)pos[tt];
#pragma unroll
        for (int nt = 0; nt < 4; ++nt) {
          const int col = ncol0 + nt * 16 + lane15;
          const int h = col >> 6, dcol = col & 63;
          float sn, cn;
          __sincosf(posf * invf[nt], &sn, &cn);
          const float self = acc[mt][nt][r];
          const float part = __shfl_xor(self, 1, 64);  // RoPE pair partner
          const float res = (dcol & 1) ? (part * sn + self * cn)
                                       : (self * cn - part * sn);
          dst[(((size_t)((bb * 16 + h) * 2048 + tt)) << 6) + dcol] = f2bf(res * sc);
        }
      }
    }
  }
}

// ---------------------------------------------------------------------------
// NT GEMM (out-proj): 64x128 tile -> 1024 blocks (4/CU). fp32 out.
// ---------------------------------------------------------------------------
__global__ __launch_bounds__(256) void gemm_bt(const u16* __restrict__ A,
                                               const u16* __restrict__ B,
                                               float* __restrict__ C,
                                               int M, int N, int K) {
  __shared__ __align__(16) u16 As[64 * 32];    // 4 KB
  __shared__ __align__(16) u16 Bs[128 * 32];   // 8 KB
  const int tid = threadIdx.x;
  const int m0 = blockIdx.y << 6;
  const int n0 = blockIdx.x << 7;
  const int w = tid >> 6, L = tid & 63;
  const int wm = (w >> 1) << 5, wn = (w & 1) << 6;  // wave: 32x64
  const int lane15 = L & 15, quad = L >> 4;
  const int koff = quad << 3;

  f32x4 acc[2][4] = {};

  const int s0 = tid, s1 = tid + 256;
  const u16* A0 = A + (size_t)(m0 + (s0 >> 2)) * K + ((s0 & 3) << 3);
  const u16* B0 = B + (size_t)(n0 + (s0 >> 2)) * K + ((s0 & 3) << 3);
  const u16* B1 = B + (size_t)(n0 + (s1 >> 2)) * K + ((s1 & 3) << 3);
  u16* asd0 = &As[s0 * 8];
  u16* bsd0 = &Bs[s0 * 8]; u16* bsd1 = &Bs[s1 * 8];

  for (int k0 = 0; k0 < K; k0 += 32) {
    __syncthreads();
    glds16(A0 + k0, asd0);
    glds16(B0 + k0, bsd0);
    glds16(B1 + k0, bsd1);
    __syncthreads();
    short8 a[2], b[4];
#pragma unroll
    for (int mt = 0; mt < 2; ++mt)
      a[mt] = *(const short8*)&As[(wm + mt * 16 + lane15) * 32 + koff];
#pragma unroll
    for (int nt = 0; nt < 4; ++nt)
      b[nt] = *(const short8*)&Bs[(wn + nt * 16 + lane15) * 32 + koff];
#pragma unroll
    for (int mt = 0; mt < 2; ++mt)
#pragma unroll
      for (int nt = 0; nt < 4; ++nt)
        acc[mt][nt] =
            __builtin_amdgcn_mfma_f32_16x16x32_bf16(a[mt], b[nt], acc[mt][nt], 0, 0, 0);
  }

#pragma unroll
  for (int mt = 0; mt < 2; ++mt) {
    const int rbase = m0 + wm + mt * 16 + (quad << 2);
#pragma unroll
    for (int nt = 0; nt < 4; ++nt) {
      const int col = n0 + wn + nt * 16 + lane15;
#pragma unroll
      for (int r = 0; r < 4; ++r)
        C[(size_t)(rbase + r) * N + col] = acc[mt][nt][r];
    }
  }
}

// ---------------------------------------------------------------------------
// V transpose: (b,t,h*64+d) -> (b*16+h, d, t) via LDS 64x64 tile.
// ---------------------------------------------------------------------------
__global__ __launch_bounds__(256) void transpose_v(const u16* __restrict__ Vlin,
                                                   u16* __restrict__ Vt) {
  __shared__ __align__(16) u16 tile[64][68];
  const int tid = threadIdx.x;
  const int bh = blockIdx.y, b = bh >> 4, h = bh & 15;
  const int t0 = blockIdx.x << 6;
#pragma unroll
  for (int i = 0; i < 4; ++i) {
    int s = tid + (i << 8);
    int tl = s >> 4, c4 = (s & 15) << 2;
    *(uint2*)&tile[tl][c4] =
        *(const uint2*)(Vlin + (((size_t)(b * 2048 + t0 + tl)) << 10) + (h << 6) + c4);
  }
  __syncthreads();
#pragma unroll
  for (int i = 0; i < 4; ++i) {
    int s = tid + (i << 8);
    int d = s >> 4, t4 = (s & 15) << 2;
    uint2 o;
    o.x = (unsigned)tile[t4 + 0][d] | ((unsigned)tile[t4 + 1][d] << 16);
    o.y = (unsigned)tile[t4 + 2][d] | ((unsigned)tile[t4 + 3][d] << 16);
    *(uint2*)(Vt + (((size_t)(bh * 64 + d)) << 11) + t0 + t4) = o;
  }
}

// ---------------------------------------------------------------------------
// Flash attention v5 (causal). 1024 blocks: qt = 15-(id>>6), bh = id&63.
// Q-tile 128; single-buffered K/V (register prefetch, 2 barriers/iter);
// per-(wave,half) P regions; K/V LDS rows padded to 72; truncating P pack;
// max-free softmax. LDS 34816 B -> 4 blocks/CU resident.
// ---------------------------------------------------------------------------
__global__ __launch_bounds__(256) void flash_attn(const u16* __restrict__ Q,
                                                  const u16* __restrict__ Kk,
                                                  const u16* __restrict__ Vt,
                                                  u16* __restrict__ O) {
  __shared__ __align__(16) u16 Ksm[64 * 72];      // [key][d] pad 72
  __shared__ __align__(16) u16 Vsm[64 * 72];      // [d][key] pad 72
  __shared__ __align__(16) u16 Psm[8][16 * 64];   // per (wave,half) P
  const int tid = threadIdx.x;
  const int w = tid >> 6, L = tid & 63;
  const int lane15 = L & 15, quad = L >> 4;
  const int qt = 15 - (blockIdx.x >> 6);
  const int bh = blockIdx.x & 63;
  const int b = bh >> 4, h = bh & 15;
  const int rq = lane15 >> 2;  // row-quad for P read swizzle
  const int nkt = 2 * qt + 2;

  const int s0 = tid, s1 = tid + 256;
  const u16* kbase = Kk + ((size_t)bh << 17);
  const u16* kp0 = kbase + s0 * 8;
  const u16* kp1 = kbase + s1 * 8;
  const u16* vbase = Vt + ((size_t)bh << 17);
  const u16* vp0 = vbase + (size_t)(s0 >> 3) * 2048 + (s0 & 7) * 8;
  const u16* vp1 = vbase + (size_t)(s1 >> 3) * 2048 + (s1 & 7) * 8;
  const int d0 = (s0 >> 3) * 72 + (s0 & 7) * 8;
  const int d1 = (s1 >> 3) * 72 + (s1 & 7) * 8;

  const size_t qrow = (size_t)bh * 2048 + qt * 128 + w * 32;
  short8 qa[2][2];
#pragma unroll
  for (int hf = 0; hf < 2; ++hf) {
    const size_t qb = (qrow + hf * 16 + lane15) << 6;
    qa[hf][0] = *(const short8*)(Q + qb + (quad << 3));
    qa[hf][1] = *(const short8*)(Q + qb + 32 + (quad << 3));
  }

  uint4 kr0 = *(const uint4*)kp0;
  uint4 kr1 = *(const uint4*)kp1;
  uint4 vr0 = *(const uint4*)vp0;
  uint4 vr1 = *(const uint4*)vp1;
  *(uint4*)&Ksm[d0] = kr0; *(uint4*)&Ksm[d1] = kr1;
  *(uint4*)&Vsm[d0] = vr0; *(uint4*)&Vsm[d1] = vr1;
  __syncthreads();

  f32x4 o_acc[2][4] = {};
  float l_part[2][4] = {};

  for (int kt = 0; kt < nkt; ++kt) {
    if (kt + 1 < nkt) {
      kr0 = *(const uint4*)(kp0 + (size_t)(kt + 1) * 4096);
      kr1 = *(const uint4*)(kp1 + (size_t)(kt + 1) * 4096);
      vr0 = *(const uint4*)(vp0 + (kt + 1) * 64);
      vr1 = *(const uint4*)(vp1 + (kt + 1) * 64);
    }

    short8 kb[4][2];
#pragma unroll
    for (int nt = 0; nt < 4; ++nt) {
      kb[nt][0] = *(const short8*)&Ksm[(nt * 16 + lane15) * 72 + (quad << 3)];
      kb[nt][1] = *(const short8*)&Ksm[(nt * 16 + lane15) * 72 + 32 + (quad << 3)];
    }

#pragma unroll
    for (int hf = 0; hf < 2; ++hf) {
      const int B0 = qt * 128 + w * 32 + hf * 16;
      if (kt * 64 > B0 + 15) continue;
      u16* pw = Psm[w * 2 + hf];

      f32x4 sc[4];
#pragma unroll
      for (int nt = 0; nt < 4; ++nt) {
        f32x4 a = {};
        a = __builtin_amdgcn_mfma_f32_16x16x32_bf16(qa[hf][0], kb[nt][0], a, 0, 0, 0);
        a = __builtin_amdgcn_mfma_f32_16x16x32_bf16(qa[hf][1], kb[nt][1], a, 0, 0, 0);
        sc[nt] = a;
      }

      if (kt * 64 + 63 > B0) {
#pragma unroll
        for (int nt = 0; nt < 4; ++nt)
#pragma unroll
          for (int r = 0; r < 4; ++r) {
            const int row = B0 + (quad << 2) + r;
            const int key = kt * 64 + nt * 16 + lane15;
            if (key > row) sc[nt][r] = -1e30f;
          }
      }

      asm volatile("" ::: "memory");
#pragma unroll
      for (int nt = 0; nt < 4; ++nt) {
        const int colsw = ((nt ^ quad) << 4) + lane15;
#pragma unroll
        for (int r = 0; r < 4; ++r) {
          const float p = EXP2(sc[nt][r]);
          l_part[hf][r] += p;
          pw[((quad << 2) + r) * 64 + colsw] = (u16)(__float_as_uint(p) >> 16);
        }
      }
      asm volatile("" ::: "memory");

#pragma unroll
      for (int ks = 0; ks < 2; ++ks) {
        const short8 pa =
            *(const short8*)&pw[lane15 * 64 + ((ks * 32 + quad * 8) ^ (rq << 4))];
#pragma unroll
        for (int dt = 0; dt < 4; ++dt) {
          const short8 vb =
              *(const short8*)&Vsm[(dt * 16 + lane15) * 72 + ks * 32 + quad * 8];
          o_acc[hf][dt] =
              __builtin_amdgcn_mfma_f32_16x16x32_bf16(pa, vb, o_acc[hf][dt], 0, 0, 0);
        }
      }
    }

    if (kt + 1 < nkt) {
      __syncthreads();
      *(uint4*)&Ksm[d0] = kr0; *(uint4*)&Ksm[d1] = kr1;
      *(uint4*)&Vsm[d0] = vr0; *(uint4*)&Vsm[d1] = vr1;
      __syncthreads();
    }
  }

#pragma unroll
  for (int hf = 0; hf < 2; ++hf) {
#pragma unroll
    for (int r = 0; r < 4; ++r) {
      float l = l_part[hf][r];
#pragma unroll
      for (int off = 1; off < 16; off <<= 1) l += __shfl_xor(l, off, 64);
      const float inv = 1.f / l;
      const int t = qt * 128 + w * 32 + hf * 16 + (quad << 2) + r;
      const size_t obase = (((size_t)b * 2048 + t) << 10) + (h << 6);
#pragma unroll
      for (int dt = 0; dt < 4; ++dt)
        O[obase + dt * 16 + lane15] = f2bf(o_acc[hf][dt][r] * inv);
    }
  }
}

// ---------------------------------------------------------------------------
extern "C" void kernel_launch(void* const* d_in, const int* in_sizes, int n_in,
                              void* d_out, int out_size, void* d_ws, size_t ws_size,
                              hipStream_t stream) {
  const float* X  = (const float*)d_in[0];
  const int* pos  = (const int*)d_in[1];
  const float* Wq = (const float*)d_in[2];
  const float* Wk = (const float*)d_in[3];
  const float* Wv = (const float*)d_in[4];
  const float* Wo = (const float*)d_in[5];
  float* out = (float*)d_out;

  char* ws = (char*)d_ws;
  const size_t SZ = (size_t)8192 * 1024 * sizeof(u16);  // 16 MB per (B,T,D) bf16
  const size_t WSZ = (size_t)1024 * 1024 * sizeof(u16); //  2 MB per (D,D) bf16
  u16* Vlin = (u16*)(ws + 0 * SZ);
  u16* Qr   = (u16*)(ws + 1 * SZ);
  u16* Kr   = (u16*)(ws + 2 * SZ);
  u16* Vt   = (u16*)(ws + 3 * SZ);
  u16* Xb   = (u16*)(ws + 4 * SZ);
  u16* Oh   = Vlin;  // Vlin dead after transpose_v
  char* wtail = ws + 5 * SZ;
  u16* Wqkvb = (u16*)(wtail);                 // packed [Wq;Wk;Wv] 3072x1024
  u16* Wob   = (u16*)(wtail + 3 * WSZ);

  const dim3 blk(256);

  cvt_all<<<6144, blk, 0, stream>>>(X, Wq, Wk, Wv, Wo, Xb, Wqkvb, Wob);
  gemm_qkv<<<dim3(24, 64), blk, 0, stream>>>(Xb, Wqkvb, pos, Qr, Kr, Vlin);
  transpose_v<<<dim3(32, 64), blk, 0, stream>>>(Vlin, Vt);
  flash_attn<<<1024, blk, 0, stream>>>(Qr, Kr, Vt, Oh);
  gemm_bt<<<dim3(8, 128), blk, 0, stream>>>(Oh, Wob, out, 8192, 1024, 1024);
}